// Round 1
// baseline (151.775 us; speedup 1.0000x reference)
//
#include <hip/hip_runtime.h>
#include <math.h>

#define N_ 32
#define C_ 256
#define H_ 56
#define W_ 56
#define HW_ (H_*W_)          // 3136
#define CHW_ (C_*HW_)        // 802816
#define NHW_ (N_*HW_)        // 100352
#define NCW_ (N_*C_*W_)      // 458752
#define NHC_ (N_*H_*C_)      // 458752
#define BN_EPS_ 1e-5f

// ---- pooling over C: x[N,C,H,W] -> maxC/meanC [N,H,W] ----
__global__ void pool_c_k(const float* __restrict__ x, float* __restrict__ maxC,
                         float* __restrict__ meanC) {
    int t = blockIdx.x * 256 + threadIdx.x;        // 0..NHW-1
    int n = t / HW_, hw = t % HW_;
    const float* p = x + (size_t)n * CHW_ + hw;
    float mx = -INFINITY, sm = 0.f;
    #pragma unroll 8
    for (int c = 0; c < C_; ++c) {
        float v = p[c * HW_];
        mx = fmaxf(mx, v);
        sm += v;
    }
    maxC[t] = mx;
    meanC[t] = sm * (1.f / C_);
}

// ---- pooling over H: x[N,C,H,W] -> maxH/meanH [N,C,W] ----
__global__ void pool_h_k(const float* __restrict__ x, float* __restrict__ maxH,
                         float* __restrict__ meanH) {
    int t = blockIdx.x * 256 + threadIdx.x;        // 0..NCW-1
    int n = t / (C_ * W_);
    int r = t % (C_ * W_);
    int c = r / W_, w = r % W_;
    const float* p = x + (size_t)n * CHW_ + c * HW_ + w;
    float mx = -INFINITY, sm = 0.f;
    #pragma unroll 8
    for (int h = 0; h < H_; ++h) {
        float v = p[h * W_];
        mx = fmaxf(mx, v);
        sm += v;
    }
    maxH[t] = mx;
    meanH[t] = sm * (1.f / H_);
}

// ---- pooling over W: x[N,C,H,W] -> maxW/meanW [N,H,C] ----
__global__ void pool_w_k(const float* __restrict__ x, float* __restrict__ maxW,
                         float* __restrict__ meanW) {
    int n = blockIdx.x / H_;
    int h = blockIdx.x % H_;
    int c = threadIdx.x;                            // 0..255
    const float4* p = (const float4*)(x + (size_t)n * CHW_ + c * HW_ + h * W_);
    float mx = -INFINITY, sm = 0.f;
    #pragma unroll
    for (int i = 0; i < W_ / 4; ++i) {
        float4 v = p[i];
        mx = fmaxf(mx, fmaxf(fmaxf(v.x, v.y), fmaxf(v.z, v.w)));
        sm += v.x + v.y + v.z + v.w;
    }
    int o = (n * H_ + h) * C_ + c;
    maxW[o] = mx;
    meanW[o] = sm * (1.f / W_);
}

// ---- ECA input: y[n,c] = mean over h of meanW[n,h,c] (== mean over H,W) ----
__global__ void eca_y_k(const float* __restrict__ meanW, float* __restrict__ y) {
    int t = blockIdx.x * 256 + threadIdx.x;        // 0..N*C-1
    int n = t / C_, c = t % C_;
    const float* p = meanW + (size_t)n * H_ * C_ + c;
    float sm = 0.f;
    #pragma unroll 8
    for (int h = 0; h < H_; ++h) sm += p[h * C_];
    y[t] = sm * (1.f / H_);
}

// ---- 7x7 conv over [R,Cc] image with 2 in-channels (max, mean), BN, sigmoid ----
__global__ void conv7_bn_sig_k(const float* __restrict__ p0, const float* __restrict__ p1,
                               const float* __restrict__ wt, const float* __restrict__ g,
                               const float* __restrict__ b, const float* __restrict__ m,
                               const float* __restrict__ v, float* __restrict__ out,
                               int R, int Cc) {
    int t = blockIdx.x * 256 + threadIdx.x;
    int per = R * Cc;
    int n = t / per;
    int r2 = t % per;
    int i = r2 / Cc, j = r2 % Cc;
    const float* b0 = p0 + (size_t)n * per;
    const float* b1 = p1 + (size_t)n * per;
    float acc = 0.f;
    #pragma unroll
    for (int ki = 0; ki < 7; ++ki) {
        int ii = i + ki - 3;
        if (ii < 0 || ii >= R) continue;
        #pragma unroll
        for (int kj = 0; kj < 7; ++kj) {
            int jj = j + kj - 3;
            if (jj < 0 || jj >= Cc) continue;
            float w0 = wt[ki * 7 + kj];
            float w1 = wt[49 + ki * 7 + kj];
            int idx = ii * Cc + jj;
            acc += b0[idx] * w0 + b1[idx] * w1;
        }
    }
    float o = (acc - m[0]) * rsqrtf(v[0] + BN_EPS_) * g[0] + b[0];
    out[t] = 1.f / (1.f + expf(-o));
}

// ---- ECA: per-n sort desc (stable), conv1d k=5 pad2, sigmoid, scatter back ----
__global__ void eca_sort_conv_k(const float* __restrict__ y, const float* __restrict__ weca,
                                float* __restrict__ gate) {
    __shared__ float sv[C_];
    __shared__ int si[C_];
    int tid = threadIdx.x;
    int n = blockIdx.x;
    sv[tid] = y[n * C_ + tid];
    si[tid] = tid;
    __syncthreads();
    for (int k = 2; k <= C_; k <<= 1) {
        for (int j = k >> 1; j > 0; j >>= 1) {
            int ixj = tid ^ j;
            if (ixj > tid) {
                float v1 = sv[tid], v2 = sv[ixj];
                int i1 = si[tid], i2 = si[ixj];
                // "before" in target order: descending value, ties -> lower index first
                bool before = (v1 > v2) || (v1 == v2 && i1 < i2);
                bool dir = ((tid & k) == 0);
                if (dir ? !before : before) {
                    sv[tid] = v2; sv[ixj] = v1;
                    si[tid] = i2; si[ixj] = i1;
                }
            }
            __syncthreads();
        }
    }
    float o = 0.f;
    #pragma unroll
    for (int j = 0; j < 5; ++j) {
        int p = tid + j - 2;
        if (p >= 0 && p < C_) o += sv[p] * weca[j];
    }
    float sg = 1.f / (1.f + expf(-o));
    gate[n * C_ + si[tid]] = sg;
}

// ---- final apply: out = x * (a0*s_s[n,h,w] + a1*s_h[n,c,w] + a2*s_w[n,h,c] + a3*g[n,c]) ----
__global__ void apply_k(const float* __restrict__ x, const float* __restrict__ s_s,
                        const float* __restrict__ s_h, const float* __restrict__ s_w,
                        const float* __restrict__ gate, float* __restrict__ out) {
    int t = blockIdx.x * 256 + threadIdx.x;        // indexes float4
    int f = t * 4;
    int n = f / CHW_;
    int rem = f % CHW_;
    int c = rem / HW_;
    int hw = rem % HW_;
    int h = hw / W_;
    int w = hw % W_;
    float4 xv = ((const float4*)x)[t];
    float4 s4 = *(const float4*)(s_s + (size_t)n * HW_ + hw);
    float4 h4 = *(const float4*)(s_h + ((size_t)n * C_ + c) * W_ + w);
    float sw = s_w[((size_t)n * H_ + h) * C_ + c];
    float ge = gate[n * C_ + c];
    float base = 0.24365f * sw + 0.27173f * ge;
    float4 o;
    o.x = xv.x * (0.23779f * s4.x + 0.24695f * h4.x + base);
    o.y = xv.y * (0.23779f * s4.y + 0.24695f * h4.y + base);
    o.z = xv.z * (0.23779f * s4.z + 0.24695f * h4.z + base);
    o.w = xv.w * (0.23779f * s4.w + 0.24695f * h4.w + base);
    ((float4*)out)[t] = o;
    (void)w;
}

extern "C" void kernel_launch(void* const* d_in, const int* in_sizes, int n_in,
                              void* d_out, int out_size, void* d_ws, size_t ws_size,
                              hipStream_t stream) {
    const float* x     = (const float*)d_in[0];
    // d_in[1] 'weight' is unused by the reference
    const float* w_h   = (const float*)d_in[2];
    const float* g_h   = (const float*)d_in[3];
    const float* b_h   = (const float*)d_in[4];
    const float* m_h   = (const float*)d_in[5];
    const float* v_h   = (const float*)d_in[6];
    const float* w_w   = (const float*)d_in[7];
    const float* g_w   = (const float*)d_in[8];
    const float* b_w   = (const float*)d_in[9];
    const float* m_w   = (const float*)d_in[10];
    const float* v_w   = (const float*)d_in[11];
    const float* w_s   = (const float*)d_in[12];
    const float* g_s   = (const float*)d_in[13];
    const float* b_s   = (const float*)d_in[14];
    const float* m_s   = (const float*)d_in[15];
    const float* v_s   = (const float*)d_in[16];
    const float* w_eca = (const float*)d_in[17];
    float* out = (float*)d_out;

    float* ws    = (float*)d_ws;
    float* maxC  = ws;                  // NHW
    float* meanC = maxC  + NHW_;        // NHW
    float* maxH  = meanC + NHW_;        // NCW
    float* meanH = maxH  + NCW_;        // NCW
    float* maxW  = meanH + NCW_;        // NHC
    float* meanW = maxW  + NHC_;        // NHC
    float* s_s   = meanW + NHC_;        // NHW
    float* s_h   = s_s   + NHW_;        // NCW
    float* s_w   = s_h   + NCW_;        // NHC
    float* yv    = s_w   + NHC_;        // N*C
    float* gate  = yv    + N_ * C_;     // N*C

    pool_c_k<<<NHW_ / 256, 256, 0, stream>>>(x, maxC, meanC);
    pool_h_k<<<NCW_ / 256, 256, 0, stream>>>(x, maxH, meanH);
    pool_w_k<<<N_ * H_, 256, 0, stream>>>(x, maxW, meanW);
    eca_y_k<<<(N_ * C_) / 256, 256, 0, stream>>>(meanW, yv);

    conv7_bn_sig_k<<<NHW_ / 256, 256, 0, stream>>>(maxC, meanC, w_s, g_s, b_s, m_s, v_s,
                                                   s_s, H_, W_);
    conv7_bn_sig_k<<<NCW_ / 256, 256, 0, stream>>>(maxH, meanH, w_h, g_h, b_h, m_h, v_h,
                                                   s_h, C_, W_);
    conv7_bn_sig_k<<<NHC_ / 256, 256, 0, stream>>>(maxW, meanW, w_w, g_w, b_w, m_w, v_w,
                                                   s_w, H_, C_);
    eca_sort_conv_k<<<N_, 256, 0, stream>>>(yv, w_eca, gate);

    apply_k<<<(N_ * CHW_ / 4) / 256, 256, 0, stream>>>(x, s_s, s_h, s_w, gate, out);
}

// Round 2
// 116.775 us; speedup vs baseline: 1.2997x; 1.2997x over previous
//
#include <hip/hip_runtime.h>
#include <math.h>

#define N_ 32
#define C_ 256
#define H_ 56
#define W_ 56
#define HW_ (H_*W_)          // 3136
#define CHW_ (C_*HW_)        // 802816
#define NHW_ (N_*HW_)        // 100352
#define NCW_ (N_*C_*W_)      // 458752
#define NHC_ (N_*H_*C_)      // 458752
#define BN_EPS_ 1e-5f

#define TILE_LD 57           // padded row stride (gcd(57,32)=1 -> conflict-free col reads)

// ---- fused pooling kernel ----
// blocks [0, N*C): grid-(n,c) -> pool over H (maxH/meanH [n,c,w]),
//                   pool over W (maxW/meanW [n,h,c]), y[n,c] = global mean
// blocks [N*C, N*C + NHW/4/256): vectorized pool over C (maxC/meanC [n,h,w])
__global__ __launch_bounds__(256) void pools_k(
        const float* __restrict__ x,
        float* __restrict__ maxH, float* __restrict__ meanH,
        float* __restrict__ maxW, float* __restrict__ meanW,
        float* __restrict__ maxC, float* __restrict__ meanC,
        float* __restrict__ y) {
    int b = blockIdx.x;
    int tid = threadIdx.x;
    if (b < N_ * C_) {
        __shared__ float tile[H_ * TILE_LD];
        __shared__ float rowsum[H_];
        int n = b / C_, c = b % C_;
        const float4* src = (const float4*)(x + ((size_t)n * C_ + c) * HW_);
        // stage channel plane [H][W] into padded LDS
        for (int j = tid; j < HW_ / 4; j += 256) {
            float4 v = src[j];
            int h = j / (W_ / 4);
            int w4 = (j - h * (W_ / 4)) * 4;
            float* d = &tile[h * TILE_LD + w4];
            d[0] = v.x; d[1] = v.y; d[2] = v.z; d[3] = v.w;
        }
        __syncthreads();
        // reduce over H for each w  (lanes 0..55 of wave 0; addresses consecutive -> no conflict)
        if (tid < W_) {
            int w = tid;
            float mx = -INFINITY, sm = 0.f;
            #pragma unroll 8
            for (int h = 0; h < H_; ++h) {
                float v = tile[h * TILE_LD + w];
                mx = fmaxf(mx, v); sm += v;
            }
            int o = (n * C_ + c) * W_ + w;
            maxH[o] = mx; meanH[o] = sm * (1.f / H_);
        }
        // reduce over W for each h (wave 1; per-lane rows, stride 57 -> spread banks)
        if (tid >= 64 && tid < 64 + H_) {
            int h = tid - 64;
            const float* r = &tile[h * TILE_LD];
            float mx = -INFINITY, sm = 0.f;
            #pragma unroll 8
            for (int w = 0; w < W_; ++w) {
                float v = r[w];
                mx = fmaxf(mx, v); sm += v;
            }
            int o = (n * H_ + h) * C_ + c;
            maxW[o] = mx; meanW[o] = sm * (1.f / W_);
            rowsum[h] = sm;
        }
        __syncthreads();
        if (tid == 0) {
            float t = 0.f;
            #pragma unroll 8
            for (int h = 0; h < H_; ++h) t += rowsum[h];
            y[n * C_ + c] = t * (1.f / HW_);
        }
    } else {
        // pool over C, float4 over hw
        int t = (b - N_ * C_) * 256 + tid;         // 0 .. NHW/4-1
        int n = t / (HW_ / 4);
        int q = t - n * (HW_ / 4);                  // float4 index within hw
        const float* p = x + (size_t)n * CHW_ + q * 4;
        float4 mx = make_float4(-INFINITY, -INFINITY, -INFINITY, -INFINITY);
        float4 sm = make_float4(0.f, 0.f, 0.f, 0.f);
        #pragma unroll 4
        for (int c = 0; c < C_; ++c) {
            float4 v = *(const float4*)(p + (size_t)c * HW_);
            mx.x = fmaxf(mx.x, v.x); mx.y = fmaxf(mx.y, v.y);
            mx.z = fmaxf(mx.z, v.z); mx.w = fmaxf(mx.w, v.w);
            sm.x += v.x; sm.y += v.y; sm.z += v.z; sm.w += v.w;
        }
        sm.x *= (1.f / C_); sm.y *= (1.f / C_); sm.z *= (1.f / C_); sm.w *= (1.f / C_);
        ((float4*)(maxC))[t]  = mx;
        ((float4*)(meanC))[t] = sm;
    }
}

// ---- conv 7x7 + BN + sigmoid over one [R,Cc] image pair ----
__device__ __forceinline__ void conv7_part(int t, const float* __restrict__ p0,
                                           const float* __restrict__ p1,
                                           const float* __restrict__ wt,
                                           float g, float bb, float m, float v,
                                           float* __restrict__ out, int R, int Cc) {
    int per = R * Cc;
    int n = t / per;
    int r2 = t - n * per;
    int i = r2 / Cc, j = r2 - i * Cc;
    const float* b0 = p0 + (size_t)n * per;
    const float* b1 = p1 + (size_t)n * per;
    float acc = 0.f;
    #pragma unroll
    for (int ki = 0; ki < 7; ++ki) {
        int ii = i + ki - 3;
        if (ii < 0 || ii >= R) continue;
        #pragma unroll
        for (int kj = 0; kj < 7; ++kj) {
            int jj = j + kj - 3;
            if (jj < 0 || jj >= Cc) continue;
            int idx = ii * Cc + jj;
            acc += b0[idx] * wt[ki * 7 + kj] + b1[idx] * wt[49 + ki * 7 + kj];
        }
    }
    float o = (acc - m) * rsqrtf(v + BN_EPS_) * g + bb;
    out[t] = 1.f / (1.f + expf(-o));
}

#define NB_SS (NHW_ / 256)            // 392
#define NB_SH (NCW_ / 256)            // 1792
#define NB_SW (NHC_ / 256)            // 1792

// ---- fused: 3 gate convs + ECA sort/conv/unsort, dispatched by block range ----
__global__ __launch_bounds__(256) void conv_eca_k(
        const float* __restrict__ maxC, const float* __restrict__ meanC,
        const float* __restrict__ maxH, const float* __restrict__ meanH,
        const float* __restrict__ maxW, const float* __restrict__ meanW,
        const float* __restrict__ w_s, const float* __restrict__ g_s,
        const float* __restrict__ b_s, const float* __restrict__ m_s,
        const float* __restrict__ v_s,
        const float* __restrict__ w_h, const float* __restrict__ g_h,
        const float* __restrict__ b_h, const float* __restrict__ m_h,
        const float* __restrict__ v_h,
        const float* __restrict__ w_w, const float* __restrict__ g_w,
        const float* __restrict__ b_w, const float* __restrict__ m_w,
        const float* __restrict__ v_w,
        const float* __restrict__ y, const float* __restrict__ w_eca,
        float* __restrict__ s_s, float* __restrict__ s_h, float* __restrict__ s_w,
        float* __restrict__ gate) {
    __shared__ float sv[C_];
    __shared__ int si[C_];
    int b = blockIdx.x;
    int tid = threadIdx.x;
    if (b < NB_SS) {
        conv7_part(b * 256 + tid, maxC, meanC, w_s, g_s[0], b_s[0], m_s[0], v_s[0],
                   s_s, H_, W_);
    } else if (b < NB_SS + NB_SH) {
        conv7_part((b - NB_SS) * 256 + tid, maxH, meanH, w_h, g_h[0], b_h[0], m_h[0],
                   v_h[0], s_h, C_, W_);
    } else if (b < NB_SS + NB_SH + NB_SW) {
        conv7_part((b - NB_SS - NB_SH) * 256 + tid, maxW, meanW, w_w, g_w[0], b_w[0],
                   m_w[0], v_w[0], s_w, H_, C_);
    } else {
        // ECA: bitonic sort desc (stable by index), conv1d k=5 pad 2, sigmoid, unsort
        int n = b - (NB_SS + NB_SH + NB_SW);
        sv[tid] = y[n * C_ + tid];
        si[tid] = tid;
        __syncthreads();
        for (int k = 2; k <= C_; k <<= 1) {
            for (int j = k >> 1; j > 0; j >>= 1) {
                int ixj = tid ^ j;
                if (ixj > tid) {
                    float v1 = sv[tid], v2 = sv[ixj];
                    int i1 = si[tid], i2 = si[ixj];
                    bool before = (v1 > v2) || (v1 == v2 && i1 < i2);
                    bool dir = ((tid & k) == 0);
                    if (dir ? !before : before) {
                        sv[tid] = v2; sv[ixj] = v1;
                        si[tid] = i2; si[ixj] = i1;
                    }
                }
                __syncthreads();
            }
        }
        float o = 0.f;
        #pragma unroll
        for (int j = 0; j < 5; ++j) {
            int p = tid + j - 2;
            if (p >= 0 && p < C_) o += sv[p] * w_eca[j];
        }
        gate[n * C_ + si[tid]] = 1.f / (1.f + expf(-o));
    }
}

// ---- final apply ----
__global__ __launch_bounds__(256) void apply_k(
        const float* __restrict__ x, const float* __restrict__ s_s,
        const float* __restrict__ s_h, const float* __restrict__ s_w,
        const float* __restrict__ gate, float* __restrict__ out) {
    int t = blockIdx.x * 256 + threadIdx.x;        // float4 index
    int f = t * 4;
    int n = f / CHW_;
    int rem = f - n * CHW_;
    int c = rem / HW_;
    int hw = rem - c * HW_;
    int h = hw / W_;
    int w = hw - h * W_;
    float4 xv = ((const float4*)x)[t];
    float4 s4 = *(const float4*)(s_s + (size_t)n * HW_ + hw);
    float4 h4 = *(const float4*)(s_h + ((size_t)n * C_ + c) * W_ + w);
    float sw = s_w[((size_t)n * H_ + h) * C_ + c];
    float ge = gate[n * C_ + c];
    float base = 0.24365f * sw + 0.27173f * ge;
    float4 o;
    o.x = xv.x * (0.23779f * s4.x + 0.24695f * h4.x + base);
    o.y = xv.y * (0.23779f * s4.y + 0.24695f * h4.y + base);
    o.z = xv.z * (0.23779f * s4.z + 0.24695f * h4.z + base);
    o.w = xv.w * (0.23779f * s4.w + 0.24695f * h4.w + base);
    ((float4*)out)[t] = o;
}

extern "C" void kernel_launch(void* const* d_in, const int* in_sizes, int n_in,
                              void* d_out, int out_size, void* d_ws, size_t ws_size,
                              hipStream_t stream) {
    const float* x     = (const float*)d_in[0];
    const float* w_h   = (const float*)d_in[2];
    const float* g_h   = (const float*)d_in[3];
    const float* b_h   = (const float*)d_in[4];
    const float* m_h   = (const float*)d_in[5];
    const float* v_h   = (const float*)d_in[6];
    const float* w_w   = (const float*)d_in[7];
    const float* g_w   = (const float*)d_in[8];
    const float* b_w   = (const float*)d_in[9];
    const float* m_w   = (const float*)d_in[10];
    const float* v_w   = (const float*)d_in[11];
    const float* w_s   = (const float*)d_in[12];
    const float* g_s   = (const float*)d_in[13];
    const float* b_s   = (const float*)d_in[14];
    const float* m_s   = (const float*)d_in[15];
    const float* v_s   = (const float*)d_in[16];
    const float* w_eca = (const float*)d_in[17];
    float* out = (float*)d_out;

    float* ws    = (float*)d_ws;
    float* maxC  = ws;                  // NHW
    float* meanC = maxC  + NHW_;        // NHW
    float* maxH  = meanC + NHW_;        // NCW
    float* meanH = maxH  + NCW_;        // NCW
    float* maxW  = meanH + NCW_;        // NHC
    float* meanW = maxW  + NHC_;        // NHC
    float* s_s   = meanW + NHC_;        // NHW
    float* s_h   = s_s   + NHW_;        // NCW
    float* s_w   = s_h   + NCW_;        // NHC
    float* yv    = s_w   + NHC_;        // N*C
    float* gate  = yv    + N_ * C_;     // N*C

    int pools_blocks = N_ * C_ + (NHW_ / 4) / 256;                 // 8192 + 98
    pools_k<<<pools_blocks, 256, 0, stream>>>(x, maxH, meanH, maxW, meanW,
                                              maxC, meanC, yv);

    int conv_blocks = NB_SS + NB_SH + NB_SW + N_;                  // 392+1792+1792+32
    conv_eca_k<<<conv_blocks, 256, 0, stream>>>(maxC, meanC, maxH, meanH, maxW, meanW,
                                                w_s, g_s, b_s, m_s, v_s,
                                                w_h, g_h, b_h, m_h, v_h,
                                                w_w, g_w, b_w, m_w, v_w,
                                                yv, w_eca, s_s, s_h, s_w, gate);

    apply_k<<<(N_ * CHW_ / 4) / 256, 256, 0, stream>>>(x, s_s, s_h, s_w, gate, out);
}